// Round 9
// baseline (243.152 us; speedup 1.0000x reference)
//
#include <hip/hip_runtime.h>
#include <hip/hip_fp16.h>

typedef unsigned short u16;
typedef unsigned int   u32;
typedef _Float16 f16;
typedef __attribute__((ext_vector_type(8))) f16 f16x8;
typedef __attribute__((ext_vector_type(2))) f16 h2;
typedef __attribute__((ext_vector_type(4))) float f32x4;

#define NN 50000
#define EE 1600000
#define DD 128
#define DYY 64
#define NB 196      // dst buckets: dst>>8
#define EPB 8192    // edges per bucketing chunk
#define GB 196      // ceil(EE/EPB)
#define MAXD 160    // per-wave LDS edge cache
#define NTILE 3125  // 50000/16 row tiles (exact)
#define NFB 12500   // kF blocks: 50000/4 (1 node per wave)
#define GMM 782     // ceil(NTILE/4)
#define XST 144     // LDS x-tile row stride in u16 (288 B: 16B-aligned, ~4-way max)

__device__ __forceinline__ u16 f2h(float f){
  union { f16 h; u16 u; } x; x.h = (f16)f; return x.u;
}
__device__ __forceinline__ float wave_sum(float v){
  #pragma unroll
  for (int s = 32; s; s >>= 1) v += __shfl_xor(v, s, 64);
  return v;
}

// fp32 W[K=128][N=nct*16] -> fp16 MFMA B-fragment layout:
// slot s=(ks*nct+t)*64+lane holds W[ks*32+(lane>>4)*8+j][t*16+(lane&15)], j=0..7
__device__ __forceinline__ void wfrag_one(const float* __restrict__ W, u16* __restrict__ Wf,
                                          int nct, int s){
  int lane = s & 63;
  int t  = (s >> 6) % nct;
  int ks = (s >> 6) / nct;
  int q = lane >> 4, n = lane & 15;
  int N = nct * 16;
  u16 tmp[8];
  #pragma unroll
  for (int j = 0; j < 8; ++j)
    tmp[j] = f2h(W[(ks * 32 + q * 8 + j) * N + t * 16 + n]);
  *(uint4*)(Wf + (size_t)s * 8) = *(const uint4*)tmp;
}

// launch A: blocks 0..195 per-chunk dst-bucket histograms; 196..203 W1 frags;
// 204..211 W2; 212..215 Wout; 216: c64 = b2 @ Wout + b_out (fp32, 64 vals).
__global__ __launch_bounds__(256) void kA_prep(const int* __restrict__ dst, int* __restrict__ hist2d,
                                               const float* __restrict__ W1, const float* __restrict__ W2,
                                               const float* __restrict__ Wo,
                                               const float* __restrict__ b2, const float* __restrict__ bo,
                                               u16* __restrict__ Wf1, u16* __restrict__ Wf2,
                                               u16* __restrict__ Wfo, float* __restrict__ c64){
  int b = blockIdx.x, tid = threadIdx.x;
  if (b < GB){
    __shared__ int hist[256];
    hist[tid] = 0;
    __syncthreads();
    int e0 = b * EPB, e1 = min(e0 + EPB, EE);
    for (int e = e0 + tid; e < e1; e += 256) atomicAdd(&hist[dst[e] >> 8], 1);
    __syncthreads();
    hist2d[b * 256 + tid] = hist[tid];
  } else if (b < 204) wfrag_one(W1, Wf1, 8, (b - 196) * 256 + tid);
  else if (b < 212)   wfrag_one(W2, Wf2, 8, (b - 204) * 256 + tid);
  else if (b < 216)   wfrag_one(Wo, Wfo, 4, (b - 212) * 256 + tid);
  else if (tid < DYY){
    float s = bo[tid];
    for (int k = 0; k < DD; ++k) s += b2[k] * Wo[k * DYY + tid];
    c64[tid] = s;
  }
}

// full-tile-per-wave MFMA GEMM (layer 1, fp32 X): stages W frags into Wl,
// 4 row-tiles/block (one per wave), fused Sv/Dv epilogue.
__device__ __forceinline__ void gemm_tile(const float* __restrict__ X,
                                          const u16* __restrict__ Wf, u16* __restrict__ Hout,
                                          const float* __restrict__ as, const float* __restrict__ ad,
                                          float* __restrict__ Sv, float* __restrict__ Dv,
                                          int blk, int tid, uint4* Wl){
  const uint4* Wg = (const uint4*)Wf;
  #pragma unroll
  for (int i = 0; i < 8; ++i) Wl[tid + 256 * i] = Wg[tid + 256 * i];
  __syncthreads();
  int wv = tid >> 6, lane = tid & 63;
  int rtile = blk * 4 + wv;
  if (rtile >= NTILE) return;
  int q = lane >> 4, n = lane & 15;
  int arow = rtile * 16 + n;
  f32x4 acc[8];
  #pragma unroll
  for (int t = 0; t < 8; ++t) acc[t] = (f32x4){0.f, 0.f, 0.f, 0.f};
  union F8 { uint4 u; f16x8 v; f16 h[8]; };
  #pragma unroll
  for (int ks = 0; ks < 4; ++ks){
    int kb = ks * 32 + q * 8;
    const float* xp = X + (size_t)arow * DD + kb;
    float4 f0 = *(const float4*)xp;
    float4 f1 = *(const float4*)(xp + 4);
    F8 a;
    a.h[0] = (f16)f0.x; a.h[1] = (f16)f0.y; a.h[2] = (f16)f0.z; a.h[3] = (f16)f0.w;
    a.h[4] = (f16)f1.x; a.h[5] = (f16)f1.y; a.h[6] = (f16)f1.z; a.h[7] = (f16)f1.w;
    #pragma unroll
    for (int t = 0; t < 8; ++t){
      F8 b; b.u = Wl[(ks * 8 + t) * 64 + lane];
      acc[t] = __builtin_amdgcn_mfma_f32_16x16x32_f16(a.v, b.v, acc[t], 0, 0, 0);
    }
  }
  float ps[4] = {0, 0, 0, 0}, pd[4] = {0, 0, 0, 0};
  #pragma unroll
  for (int t = 0; t < 8; ++t){
    float a_s = as[t * 16 + n];
    float a_d = ad[t * 16 + n];
    #pragma unroll
    for (int rg = 0; rg < 4; ++rg){
      ps[rg] += acc[t][rg] * a_s;
      pd[rg] += acc[t][rg] * a_d;
    }
  }
  #pragma unroll
  for (int rg = 0; rg < 4; ++rg){
    #pragma unroll
    for (int s = 1; s < 16; s <<= 1){
      ps[rg] += __shfl_xor(ps[rg], s, 64);
      pd[rg] += __shfl_xor(pd[rg], s, 64);
    }
  }
  #pragma unroll
  for (int rg = 0; rg < 4; ++rg){
    int grow = rtile * 16 + q * 4 + rg;
    if (n == 0){ Sv[grow] = ps[rg]; Dv[grow] = pd[rg]; }
    #pragma unroll
    for (int t = 0; t < 8; ++t)
      Hout[(size_t)grow * DD + t * 16 + n] = f2h(acc[t][rg]);
  }
}

// launch BC (fused; both halves depend only on kA):
//   blocks 0..195: per-chunk bucket scan + scatter into bucket-contiguous buf
//   blocks 196..977: layer-1 GEMM tiles (fp32 X) -> Hbf1, Sv1, Dv1
__global__ __launch_bounds__(256) void kBC(const int* __restrict__ src, const int* __restrict__ dst,
                                           const int* __restrict__ hist2d,
                                           int* __restrict__ btot, int* __restrict__ bbase,
                                           u32* __restrict__ buf,
                                           const float* __restrict__ X0, const u16* __restrict__ Wf1,
                                           u16* __restrict__ Hbf1,
                                           const float* __restrict__ as1, const float* __restrict__ ad1,
                                           float* __restrict__ Sv1, float* __restrict__ Dv1){
  __shared__ __align__(16) uint4 Wl[2048];
  int b = blockIdx.x, tid = threadIdx.x;
  if (b < GB){
    int* lcur = (int*)Wl;
    int* sd   = ((int*)Wl) + 256;
    int c = b;
    int pre = 0, tot = 0;
    for (int cc = 0; cc < GB; ++cc){
      int v = hist2d[cc * 256 + tid];
      if (cc < c) pre += v;
      tot += v;
    }
    sd[tid] = tot;
    __syncthreads();
    for (int o = 1; o < 256; o <<= 1){
      int t = (tid >= o) ? sd[tid - o] : 0;
      __syncthreads();
      sd[tid] += t;
      __syncthreads();
    }
    int bb = sd[tid] - tot;
    if (c == 0){ btot[tid] = tot; bbase[tid] = bb; }
    lcur[tid] = bb + pre;
    __syncthreads();
    int e0 = c * EPB, e1 = min(e0 + EPB, EE);
    for (int e = e0 + tid; e < e1; e += 256){
      int d = dst[e];
      int pos = atomicAdd(&lcur[d >> 8], 1);
      buf[pos] = (u32)src[e] | ((u32)(d & 255) << 16);
    }
  } else {
    gemm_tile(X0, Wf1, Hbf1, as1, ad1, Sv1, Dv1, b - GB, tid, Wl);
  }
}

// launch D: per-bucket finalize -> offs/cnt/srcs
__global__ __launch_bounds__(256) void kD_finalize(const u32* __restrict__ buf,
                                                   const int* __restrict__ btot, const int* __restrict__ bbase,
                                                   int* __restrict__ offs, int* __restrict__ cnt,
                                                   u16* __restrict__ srcs){
  __shared__ int dh[256];
  __shared__ int sd[256];
  __shared__ int dcur[256];
  int tid = threadIdx.x, b = blockIdx.x;
  int n = btot[b], base = bbase[b];
  dh[tid] = 0;
  __syncthreads();
  for (int i = tid; i < n; i += 256) atomicAdd(&dh[(buf[base + i] >> 16) & 255], 1);
  __syncthreads();
  int v = dh[tid];
  sd[tid] = v;
  __syncthreads();
  for (int o = 1; o < 256; o <<= 1){
    int t = (tid >= o) ? sd[tid - o] : 0;
    __syncthreads();
    sd[tid] += t;
    __syncthreads();
  }
  int excl = sd[tid] - v;
  dcur[tid] = base + excl;
  int d = (b << 8) + tid;
  if (d < NN){ offs[d] = base + excl; cnt[d] = v; }
  __syncthreads();
  for (int i = tid; i < n; i += 256){
    u32 u = buf[base + i];
    int pos = atomicAdd(&dcur[(u >> 16) & 255], 1);
    srcs[pos] = (u16)(u & 0xffffu);
  }
}

// per-node aggregation writing the result row to LDS. EXACT r1 proven body
// (2-chain, clean traffic). Do not touch.
__device__ void agg_node_lds(const u16* __restrict__ H, const float* __restrict__ Sv,
                             const float* __restrict__ Dv, const int* __restrict__ offs,
                             const int* __restrict__ cnt, const u16* __restrict__ srcs,
                             const float* __restrict__ bias, u16* __restrict__ xrow,
                             int do_relu, int wid, int lane, int* si, float* sw){
  int off = offs[wid], c = cnt[wid];
  float dvw = Dv[wid];
  float wself = __expf(fmaxf(Sv[wid] + dvw, 0.f));
  int cf = min(c, MAXD);
  int grp = lane >> 4, cg_ = lane & 15;
  const u32* H32 = (const u32*)H;
  union F8 { uint4 u; h2 p[4]; };
  // self row: issue load early so it overlaps the weight-gather latency
  F8 rself; rself.u = (uint4){0, 0, 0, 0};
  if (grp == 0) rself.u = *(const uint4*)(H32 + (size_t)wid * 64 + cg_ * 4);
  float dl = 0.f;
  for (int j = lane; j < c; j += 64){
    int sidx = (int)srcs[off + j];
    float wgt = __expf(fmaxf(Sv[sidx] + dvw, 0.f));
    if (j < MAXD){ si[j] = sidx; sw[j] = wgt; }
    dl += wgt;
  }
  float inv = 1.f / (wave_sum(dl) + wself);
  h2 accA[4] = {(h2){0,0},(h2){0,0},(h2){0,0},(h2){0,0}};
  h2 accB[4] = {(h2){0,0},(h2){0,0},(h2){0,0},(h2){0,0}};
  if (grp == 0){
    f16 wh = (f16)(wself * inv); h2 w2 = {wh, wh};
    #pragma unroll
    for (int i = 0; i < 4; ++i) accA[i] = rself.p[i] * w2;
  }
  // main loop: 8 edges/iter, two independent load+acc chains (2x MLP)
  int base = 0;
  int nfull = cf & ~7;
  for (; base < nfull; base += 8){
    int j0 = base + grp, j1 = j0 + 4;
    int s0 = si[j0], s1 = si[j1];
    float w0 = sw[j0] * inv, w1 = sw[j1] * inv;
    F8 r0; r0.u = *(const uint4*)(H32 + (size_t)s0 * 64 + cg_ * 4);
    F8 r1; r1.u = *(const uint4*)(H32 + (size_t)s1 * 64 + cg_ * 4);
    f16 wh0 = (f16)w0; h2 w20 = {wh0, wh0};
    f16 wh1 = (f16)w1; h2 w21 = {wh1, wh1};
    #pragma unroll
    for (int i = 0; i < 4; ++i){
      accA[i] += r0.p[i] * w20;
      accB[i] += r1.p[i] * w21;
    }
  }
  for (; base < cf; base += 4){
    int j = base + grp;
    float wgt = 0.f; int sidx = 0;
    if (j < cf){ wgt = sw[j] * inv; sidx = si[j]; }
    f16 wh = (f16)wgt; h2 w2 = {wh, wh};
    F8 r; r.u = *(const uint4*)(H32 + (size_t)sidx * 64 + cg_ * 4);
    #pragma unroll
    for (int i = 0; i < 4; ++i) accA[i] += r.p[i] * w2;
  }
  for (int base2 = MAXD; base2 < c; base2 += 4){   // ultra-rare tail
    int j = base2 + grp;
    bool valid = j < c;
    int sidx = valid ? (int)srcs[off + j] : 0;
    float wgt = valid ? __expf(fmaxf(Sv[sidx] + dvw, 0.f)) * inv : 0.f;
    f16 wh = (f16)wgt; h2 w2 = {wh, wh};
    F8 r; r.u = *(const uint4*)(H32 + (size_t)sidx * 64 + cg_ * 4);
    #pragma unroll
    for (int i = 0; i < 4; ++i) accA[i] += r.p[i] * w2;
  }
  #pragma unroll
  for (int i = 0; i < 4; ++i) accA[i] += accB[i];
  union FU { h2 v; float f; };
  #pragma unroll
  for (int i = 0; i < 4; ++i){
    FU a; a.v = accA[i];
    FU o1; o1.f = __shfl_xor(a.f, 16, 64); a.v = a.v + o1.v;
    FU o2; o2.f = __shfl_xor(a.f, 32, 64); a.v = a.v + o2.v;
    accA[i] = a.v;
  }
  if (grp == 0){
    uint4 pk;
    u32* pkp = (u32*)&pk;
    #pragma unroll
    for (int qq = 0; qq < 4; ++qq){
      float o0 = (float)accA[qq].x + bias[cg_ * 8 + 2 * qq];
      float o1 = (float)accA[qq].y + bias[cg_ * 8 + 2 * qq + 1];
      if (do_relu){ o0 = fmaxf(o0, 0.f); o1 = fmaxf(o1, 0.f); }
      pkp[qq] = ((u32)f2h(o1) << 16) | (u32)f2h(o0);
    }
    *(uint4*)(xrow + cg_ * 8) = pk;   // LDS row store (2-way banks: free)
  }
}

// kE: fused agg-layer1 (x1 rows -> LDS) + layer-2 GEMM + G2 projection.
// r9: 512-thread blocks, 8 waves. Each wave aggregates only TWO nodes
// (wv*2, wv*2+1) — halves the per-wave serial chain vs the 4-node version;
// agg body unchanged. GEMM1: wave wv computes h2 col-block t=wv. GEMM2 (G2,
// 64 cols) runs on waves 0-3. __launch_bounds__(512,8): 64-VGPR budget,
// 4 blocks/CU = 32 waves resident (same occupancy as the 256x8 config).
__global__ __launch_bounds__(512, 8) void kE(const u16* __restrict__ Hbf1,
                                          const float* __restrict__ Sv1, const float* __restrict__ Dv1,
                                          const int* __restrict__ offs, const int* __restrict__ cnt,
                                          const u16* __restrict__ srcs, const float* __restrict__ b1,
                                          const u16* __restrict__ Wf2, const u16* __restrict__ Wfo,
                                          const float* __restrict__ as2, const float* __restrict__ ad2,
                                          u16* __restrict__ G2,
                                          float* __restrict__ Sv2, float* __restrict__ Dv2){
  __shared__ __align__(16) u16 Xs[16 * XST];
  __shared__ int   s_i[8][MAXD];
  __shared__ float s_w[8][MAXD];
  __shared__ float svp[16], dvp[16];
  int tid = threadIdx.x, wv = tid >> 6, lane = tid & 63;
  int rtile = blockIdx.x;
  if (tid < 16){ svp[tid] = 0.f; dvp[tid] = 0.f; }
  #pragma unroll
  for (int k = 0; k < 2; ++k){
    int r = wv * 2 + k;
    agg_node_lds(Hbf1, Sv1, Dv1, offs, cnt, srcs, b1, Xs + r * XST, 1,
                 rtile * 16 + r, lane, s_i[wv], s_w[wv]);
  }
  __syncthreads();
  // GEMM 1: h2 col-block t = wv from Wf2 (32 KB, L2-resident broadcast)
  const uint4* Wg = (const uint4*)Wf2;
  int q = lane >> 4, n = lane & 15;
  f32x4 acc = (f32x4){0.f, 0.f, 0.f, 0.f};
  union F8 { uint4 u; f16x8 v; };
  #pragma unroll
  for (int ks = 0; ks < 4; ++ks){
    F8 a; a.u = *(const uint4*)((const char*)Xs + n * (XST * 2) + ks * 64 + q * 16);
    F8 b; b.u = Wg[(ks * 8 + wv) * 64 + lane];
    acc = __builtin_amdgcn_mfma_f32_16x16x32_f16(a.v, b.v, acc, 0, 0, 0);
  }
  float ps[4], pd[4];
  {
    float a_s = as2[wv * 16 + n];
    float a_d = ad2[wv * 16 + n];
    #pragma unroll
    for (int rg = 0; rg < 4; ++rg){
      ps[rg] = acc[rg] * a_s;
      pd[rg] = acc[rg] * a_d;
    }
  }
  #pragma unroll
  for (int rg = 0; rg < 4; ++rg){
    #pragma unroll
    for (int s = 1; s < 16; s <<= 1){
      ps[rg] += __shfl_xor(ps[rg], s, 64);
      pd[rg] += __shfl_xor(pd[rg], s, 64);
    }
  }
  if (n == 0){
    #pragma unroll
    for (int rg = 0; rg < 4; ++rg){
      atomicAdd(&svp[q * 4 + rg], ps[rg]);
      atomicAdd(&dvp[q * 4 + rg], pd[rg]);
    }
  }
  __syncthreads();   // all waves done reading Xs (GEMM 1 A-frags) + svp final
  if (tid < 16){ Sv2[rtile * 16 + tid] = svp[tid]; Dv2[rtile * 16 + tid] = dvp[tid]; }
  // stage h2 tile into Xs (row = q*4+rg, col = wv*16+n)
  #pragma unroll
  for (int rg = 0; rg < 4; ++rg)
    Xs[(q * 4 + rg) * XST + wv * 16 + n] = f2h(acc[rg]);
  __syncthreads();
  // GEMM 2: G2 = h2 @ Wout on waves 0-3 (Wfo nct=4; wave wv -> cols wv*16..+16)
  if (wv < 4){
    const uint4* Wo4 = (const uint4*)Wfo;
    f32x4 g = (f32x4){0.f, 0.f, 0.f, 0.f};
    #pragma unroll
    for (int ks = 0; ks < 4; ++ks){
      F8 a; a.u = *(const uint4*)((const char*)Xs + n * (XST * 2) + ks * 64 + q * 16);
      F8 b; b.u = Wo4[(ks * 4 + wv) * 64 + lane];
      g = __builtin_amdgcn_mfma_f32_16x16x32_f16(a.v, b.v, g, 0, 0, 0);
    }
    #pragma unroll
    for (int rg = 0; rg < 4; ++rg){
      int grow = rtile * 16 + q * 4 + rg;
      G2[(size_t)grow * DYY + wv * 16 + n] = f2h(g[rg]);
    }
  }
}

// agg_node_out: layer-2 aggregation directly in projected space — gathers
// 128-B G2 rows and writes the final fp32 out row (+ c64 const). r8 body:
// 8-lane groups x uint4, 16 edges in flight per iteration.
__device__ void agg_node_out(const u16* __restrict__ G2v, const float* __restrict__ Sv,
                             const float* __restrict__ Dv, const int* __restrict__ offs,
                             const int* __restrict__ cnt, const u16* __restrict__ srcs,
                             const float* __restrict__ c64, float* __restrict__ out,
                             int wid, int lane, int* si, float* sw){
  int off = offs[wid], c = cnt[wid];
  float dvw = Dv[wid];
  float wself = __expf(fmaxf(Sv[wid] + dvw, 0.f));
  int cf = min(c, MAXD);
  int grp = lane >> 3, cg_ = lane & 7;   // 8 groups x 8 lanes; lane covers 16 B
  const u32* G = (const u32*)G2v;        // row stride 32 u32 (64 fp16)
  union F8 { uint4 u; h2 p[4]; };
  F8 rself; rself.u = (uint4){0, 0, 0, 0};
  if (grp == 0) rself.u = *(const uint4*)(G + (size_t)wid * 32 + cg_ * 4);
  float dl = 0.f;
  for (int j = lane; j < c; j += 64){
    int sidx = (int)srcs[off + j];
    float wgt = __expf(fmaxf(Sv[sidx] + dvw, 0.f));
    if (j < MAXD){ si[j] = sidx; sw[j] = wgt; }
    dl += wgt;
  }
  float inv = 1.f / (wave_sum(dl) + wself);
  h2 accA[4] = {(h2){0,0},(h2){0,0},(h2){0,0},(h2){0,0}};
  h2 accB[4] = {(h2){0,0},(h2){0,0},(h2){0,0},(h2){0,0}};
  if (grp == 0){
    f16 wh = (f16)(wself * inv); h2 w2 = {wh, wh};
    #pragma unroll
    for (int i = 0; i < 4; ++i) accA[i] = rself.p[i] * w2;
  }
  // main loop: 16 edges/iter, two independent load+acc chains per group
  int base = 0;
  int nfull = cf & ~15;
  for (; base < nfull; base += 16){
    int j0 = base + grp, j1 = j0 + 8;
    int s0 = si[j0], s1 = si[j1];
    float w0 = sw[j0] * inv, w1 = sw[j1] * inv;
    F8 r0; r0.u = *(const uint4*)(G + (size_t)s0 * 32 + cg_ * 4);
    F8 r1; r1.u = *(const uint4*)(G + (size_t)s1 * 32 + cg_ * 4);
    f16 wh0 = (f16)w0; h2 x0 = {wh0, wh0};
    f16 wh1 = (f16)w1; h2 x1 = {wh1, wh1};
    #pragma unroll
    for (int i = 0; i < 4; ++i){
      accA[i] += r0.p[i] * x0;
      accB[i] += r1.p[i] * x1;
    }
  }
  for (; base < cf; base += 8){
    int j = base + grp;
    float wgt = 0.f; int sidx = 0;
    if (j < cf){ wgt = sw[j] * inv; sidx = si[j]; }
    f16 wh = (f16)wgt; h2 w2 = {wh, wh};
    F8 r; r.u = *(const uint4*)(G + (size_t)sidx * 32 + cg_ * 4);
    #pragma unroll
    for (int i = 0; i < 4; ++i) accA[i] += r.p[i] * w2;
  }
  for (int b2i = MAXD; b2i < c; b2i += 8){   // ultra-rare tail (deg > MAXD)
    int j = b2i + grp;
    bool valid = j < c;
    int sidx = valid ? (int)srcs[off + j] : 0;
    float wgt = valid ? __expf(fmaxf(Sv[sidx] + dvw, 0.f)) * inv : 0.f;
    F8 r; r.u = *(const uint4*)(G + (size_t)sidx * 32 + cg_ * 4);
    f16 wh = (f16)wgt; h2 w2 = {wh, wh};
    #pragma unroll
    for (int i = 0; i < 4; ++i) accA[i] += r.p[i] * w2;
  }
  #pragma unroll
  for (int i = 0; i < 4; ++i) accA[i] += accB[i];
  union FU { h2 v; float f; };
  #pragma unroll
  for (int i = 0; i < 4; ++i){
    FU a; a.v = accA[i];
    FU o1; o1.f = __shfl_xor(a.f,  8, 64); a.v = a.v + o1.v;
    FU o2; o2.f = __shfl_xor(a.f, 16, 64); a.v = a.v + o2.v;
    FU o3; o3.f = __shfl_xor(a.f, 32, 64); a.v = a.v + o3.v;
    accA[i] = a.v;
  }
  if (grp == 0){
    // lane cg_ holds out[cg_*8 .. +8): 4x h2 -> 8 fp32 + c64
    float4 o0, o1v;
    const float4* cv = (const float4*)(c64 + cg_ * 8);
    o0.x = (float)accA[0].x + cv[0].x;
    o0.y = (float)accA[0].y + cv[0].y;
    o0.z = (float)accA[1].x + cv[0].z;
    o0.w = (float)accA[1].y + cv[0].w;
    o1v.x = (float)accA[2].x + cv[1].x;
    o1v.y = (float)accA[2].y + cv[1].y;
    o1v.z = (float)accA[3].x + cv[1].z;
    o1v.w = (float)accA[3].y + cv[1].w;
    float4* op = (float4*)(out + (size_t)wid * DYY + cg_ * 8);
    op[0] = o0; op[1] = o1v;
  }
}

// kF: layer-2 aggregation in projected space. r9: ONE node per wave
// (grid NN/4, 4 waves/block) — quarter the per-wave serial chain of r8.
__global__ __launch_bounds__(256, 8) void kF(const u16* __restrict__ G2,
                                          const float* __restrict__ Sv2, const float* __restrict__ Dv2,
                                          const int* __restrict__ offs, const int* __restrict__ cnt,
                                          const u16* __restrict__ srcs,
                                          const float* __restrict__ c64,
                                          float* __restrict__ out){
  __shared__ int   s_i[4][MAXD];
  __shared__ float s_w[4][MAXD];
  int tid = threadIdx.x, wv = tid >> 6, lane = tid & 63;
  agg_node_out(G2, Sv2, Dv2, offs, cnt, srcs, c64, out,
               blockIdx.x * 4 + wv, lane, s_i[wv], s_w[wv]);
}

extern "C" void kernel_launch(void* const* d_in, const int* in_sizes, int n_in,
                              void* d_out, int out_size, void* d_ws, size_t ws_size,
                              hipStream_t stream) {
  const float* node_x = (const float*)d_in[0];
  const int* ei   = (const int*)d_in[1];
  const int* srcp = ei;
  const int* dstp = ei + EE;
  const float* W1  = (const float*)d_in[2];
  const float* as1 = (const float*)d_in[3];
  const float* ad1 = (const float*)d_in[4];
  const float* b1  = (const float*)d_in[5];
  const float* W2  = (const float*)d_in[6];
  const float* as2 = (const float*)d_in[7];
  const float* ad2 = (const float*)d_in[8];
  const float* b2  = (const float*)d_in[9];
  const float* Wo  = (const float*)d_in[10];
  const float* bo  = (const float*)d_in[11];

  // workspace carve: ~28 MB. buf (6.4 MB) aliases G2 (6.4 MB exactly):
  // buf dead after kD; kE writes G2.
  char* w = (char*)d_ws;
  u16*   Hbf1  = (u16*)w;  w += (size_t)NN * DD * 2;  // 12.8 MB layer-1 h (fp16)
  u32*   buf   = (u32*)w;
  u16*   G2    = (u16*)w;  w += (size_t)EE * 4;       // 6.4 MB (= NN*DYY*2)
  float* Sv1   = (float*)w; w += (size_t)NN * 4;
  float* Dv1   = (float*)w; w += (size_t)NN * 4;
  float* Sv2   = (float*)w; w += (size_t)NN * 4;
  float* Dv2   = (float*)w; w += (size_t)NN * 4;
  int*   cnt   = (int*)w;   w += (size_t)NN * 4;
  int*   offs  = (int*)w;   w += (size_t)NN * 4;
  int*   btot  = (int*)w;   w += 1024;
  int*   bbase = (int*)w;   w += 1024;
  int*   hist2d = (int*)w;  w += GB * 256 * 4;        // 200 KB
  u16*   srcs  = (u16*)w;   w += (size_t)EE * 2;      // 3.2 MB
  u16*   Wf1   = (u16*)w;   w += 32768;
  u16*   Wf2   = (u16*)w;   w += 32768;
  u16*   Wfo   = (u16*)w;   w += 16384;
  float* c64   = (float*)w; w += 256;

  const int TB = 256;

  kA_prep    <<<217,      TB, 0, stream>>>(dstp, hist2d, W1, W2, Wo, b2, bo,
                                           Wf1, Wf2, Wfo, c64);
  kBC        <<<GB + GMM, TB, 0, stream>>>(srcp, dstp, hist2d, btot, bbase, buf,
                                           node_x, Wf1, Hbf1, as1, ad1, Sv1, Dv1);
  kD_finalize<<<NB,       TB, 0, stream>>>(buf, btot, bbase, offs, cnt, srcs);
  kE         <<<NTILE,   512, 0, stream>>>(Hbf1, Sv1, Dv1, offs, cnt, srcs, b1,
                                           Wf2, Wfo, as2, ad2, G2, Sv2, Dv2);
  kF         <<<NFB,      TB, 0, stream>>>(G2, Sv2, Dv2, offs, cnt, srcs, c64,
                                           (float*)d_out);
}

// Round 10
// 241.069 us; speedup vs baseline: 1.0086x; 1.0086x over previous
//
#include <hip/hip_runtime.h>
#include <hip/hip_fp16.h>

typedef unsigned short u16;
typedef unsigned int   u32;
typedef _Float16 f16;
typedef __attribute__((ext_vector_type(8))) f16 f16x8;
typedef __attribute__((ext_vector_type(2))) f16 h2;
typedef __attribute__((ext_vector_type(4))) float f32x4;

#define NN 50000
#define EE 1600000
#define DD 128
#define DYY 64
#define NB 196      // dst buckets: dst>>8
#define EPB 8192    // edges per bucketing chunk
#define GB 196      // ceil(EE/EPB)
#define MAXD 160    // per-wave LDS edge cache
#define NTILE 3125  // 50000/16 row tiles (exact)
#define NFB 12500   // kF blocks: 50000/4 (1 node per wave)
#define GMM 782     // ceil(NTILE/4)
#define XST 144     // LDS x-tile row stride in u16 (288 B: 16B-aligned, ~4-way max)

__device__ __forceinline__ u16 f2h(float f){
  union { f16 h; u16 u; } x; x.h = (f16)f; return x.u;
}
__device__ __forceinline__ float wave_sum(float v){
  #pragma unroll
  for (int s = 32; s; s >>= 1) v += __shfl_xor(v, s, 64);
  return v;
}

// fp32 W[K=128][N=nct*16] -> fp16 MFMA B-fragment layout:
// slot s=(ks*nct+t)*64+lane holds W[ks*32+(lane>>4)*8+j][t*16+(lane&15)], j=0..7
__device__ __forceinline__ void wfrag_one(const float* __restrict__ W, u16* __restrict__ Wf,
                                          int nct, int s){
  int lane = s & 63;
  int t  = (s >> 6) % nct;
  int ks = (s >> 6) / nct;
  int q = lane >> 4, n = lane & 15;
  int N = nct * 16;
  u16 tmp[8];
  #pragma unroll
  for (int j = 0; j < 8; ++j)
    tmp[j] = f2h(W[(ks * 32 + q * 8 + j) * N + t * 16 + n]);
  *(uint4*)(Wf + (size_t)s * 8) = *(const uint4*)tmp;
}

// launch A: blocks 0..195 per-chunk dst-bucket histograms; 196..203 W1 frags;
// 204..211 W2; 212..215 Wout; 216: c64 = b2 @ Wout + b_out (fp32, 64 vals).
__global__ __launch_bounds__(256) void kA_prep(const int* __restrict__ dst, int* __restrict__ hist2d,
                                               const float* __restrict__ W1, const float* __restrict__ W2,
                                               const float* __restrict__ Wo,
                                               const float* __restrict__ b2, const float* __restrict__ bo,
                                               u16* __restrict__ Wf1, u16* __restrict__ Wf2,
                                               u16* __restrict__ Wfo, float* __restrict__ c64){
  int b = blockIdx.x, tid = threadIdx.x;
  if (b < GB){
    __shared__ int hist[256];
    hist[tid] = 0;
    __syncthreads();
    int e0 = b * EPB, e1 = min(e0 + EPB, EE);
    for (int e = e0 + tid; e < e1; e += 256) atomicAdd(&hist[dst[e] >> 8], 1);
    __syncthreads();
    hist2d[b * 256 + tid] = hist[tid];
  } else if (b < 204) wfrag_one(W1, Wf1, 8, (b - 196) * 256 + tid);
  else if (b < 212)   wfrag_one(W2, Wf2, 8, (b - 204) * 256 + tid);
  else if (b < 216)   wfrag_one(Wo, Wfo, 4, (b - 212) * 256 + tid);
  else if (tid < DYY){
    float s = bo[tid];
    for (int k = 0; k < DD; ++k) s += b2[k] * Wo[k * DYY + tid];
    c64[tid] = s;
  }
}

// full-tile-per-wave MFMA GEMM (layer 1, fp32 X): stages W frags into Wl,
// 4 row-tiles/block (one per wave), fused Sv/Dv epilogue.
__device__ __forceinline__ void gemm_tile(const float* __restrict__ X,
                                          const u16* __restrict__ Wf, u16* __restrict__ Hout,
                                          const float* __restrict__ as, const float* __restrict__ ad,
                                          float* __restrict__ Sv, float* __restrict__ Dv,
                                          int blk, int tid, uint4* Wl){
  const uint4* Wg = (const uint4*)Wf;
  #pragma unroll
  for (int i = 0; i < 8; ++i) Wl[tid + 256 * i] = Wg[tid + 256 * i];
  __syncthreads();
  int wv = tid >> 6, lane = tid & 63;
  int rtile = blk * 4 + wv;
  if (rtile >= NTILE) return;
  int q = lane >> 4, n = lane & 15;
  int arow = rtile * 16 + n;
  f32x4 acc[8];
  #pragma unroll
  for (int t = 0; t < 8; ++t) acc[t] = (f32x4){0.f, 0.f, 0.f, 0.f};
  union F8 { uint4 u; f16x8 v; f16 h[8]; };
  #pragma unroll
  for (int ks = 0; ks < 4; ++ks){
    int kb = ks * 32 + q * 8;
    const float* xp = X + (size_t)arow * DD + kb;
    float4 f0 = *(const float4*)xp;
    float4 f1 = *(const float4*)(xp + 4);
    F8 a;
    a.h[0] = (f16)f0.x; a.h[1] = (f16)f0.y; a.h[2] = (f16)f0.z; a.h[3] = (f16)f0.w;
    a.h[4] = (f16)f1.x; a.h[5] = (f16)f1.y; a.h[6] = (f16)f1.z; a.h[7] = (f16)f1.w;
    #pragma unroll
    for (int t = 0; t < 8; ++t){
      F8 b; b.u = Wl[(ks * 8 + t) * 64 + lane];
      acc[t] = __builtin_amdgcn_mfma_f32_16x16x32_f16(a.v, b.v, acc[t], 0, 0, 0);
    }
  }
  float ps[4] = {0, 0, 0, 0}, pd[4] = {0, 0, 0, 0};
  #pragma unroll
  for (int t = 0; t < 8; ++t){
    float a_s = as[t * 16 + n];
    float a_d = ad[t * 16 + n];
    #pragma unroll
    for (int rg = 0; rg < 4; ++rg){
      ps[rg] += acc[t][rg] * a_s;
      pd[rg] += acc[t][rg] * a_d;
    }
  }
  #pragma unroll
  for (int rg = 0; rg < 4; ++rg){
    #pragma unroll
    for (int s = 1; s < 16; s <<= 1){
      ps[rg] += __shfl_xor(ps[rg], s, 64);
      pd[rg] += __shfl_xor(pd[rg], s, 64);
    }
  }
  #pragma unroll
  for (int rg = 0; rg < 4; ++rg){
    int grow = rtile * 16 + q * 4 + rg;
    if (n == 0){ Sv[grow] = ps[rg]; Dv[grow] = pd[rg]; }
    #pragma unroll
    for (int t = 0; t < 8; ++t)
      Hout[(size_t)grow * DD + t * 16 + n] = f2h(acc[t][rg]);
  }
}

// launch BC (fused; both halves depend only on kA):
//   blocks 0..195: per-chunk bucket scan + scatter into bucket-contiguous buf
//   blocks 196..977: layer-1 GEMM tiles (fp32 X) -> Hbf1, Sv1, Dv1
__global__ __launch_bounds__(256) void kBC(const int* __restrict__ src, const int* __restrict__ dst,
                                           const int* __restrict__ hist2d,
                                           int* __restrict__ btot, int* __restrict__ bbase,
                                           u32* __restrict__ buf,
                                           const float* __restrict__ X0, const u16* __restrict__ Wf1,
                                           u16* __restrict__ Hbf1,
                                           const float* __restrict__ as1, const float* __restrict__ ad1,
                                           float* __restrict__ Sv1, float* __restrict__ Dv1){
  __shared__ __align__(16) uint4 Wl[2048];
  int b = blockIdx.x, tid = threadIdx.x;
  if (b < GB){
    int* lcur = (int*)Wl;
    int* sd   = ((int*)Wl) + 256;
    int c = b;
    int pre = 0, tot = 0;
    for (int cc = 0; cc < GB; ++cc){
      int v = hist2d[cc * 256 + tid];
      if (cc < c) pre += v;
      tot += v;
    }
    sd[tid] = tot;
    __syncthreads();
    for (int o = 1; o < 256; o <<= 1){
      int t = (tid >= o) ? sd[tid - o] : 0;
      __syncthreads();
      sd[tid] += t;
      __syncthreads();
    }
    int bb = sd[tid] - tot;
    if (c == 0){ btot[tid] = tot; bbase[tid] = bb; }
    lcur[tid] = bb + pre;
    __syncthreads();
    int e0 = c * EPB, e1 = min(e0 + EPB, EE);
    for (int e = e0 + tid; e < e1; e += 256){
      int d = dst[e];
      int pos = atomicAdd(&lcur[d >> 8], 1);
      buf[pos] = (u32)src[e] | ((u32)(d & 255) << 16);
    }
  } else {
    gemm_tile(X0, Wf1, Hbf1, as1, ad1, Sv1, Dv1, b - GB, tid, Wl);
  }
}

// launch D: per-bucket finalize -> offs/cnt/srcs.
// r10: counting sort is now over (dst_local, src_segment) with seg = src>>13
// (7 segments of 8192 nodes; Hbf1 slice/segment = 2 MB < 4 MB per-XCD L2).
// srcs comes out (dst, seg)-sorted, so every consumer sweeps source segments
// in the same global order -> concurrent blocks gather from the same ~2 MB
// window and L2 captures the ~32x reuse of each source row. kE/kF unchanged.
__global__ __launch_bounds__(256) void kD_finalize(const u32* __restrict__ buf,
                                                   const int* __restrict__ btot, const int* __restrict__ bbase,
                                                   int* __restrict__ offs, int* __restrict__ cnt,
                                                   u16* __restrict__ srcs){
  __shared__ int dh[2048];     // [dst_local][seg]
  __shared__ int sd[256];
  __shared__ int dcur[2048];
  int tid = threadIdx.x, b = blockIdx.x;
  int n = btot[b], base = bbase[b];
  #pragma unroll
  for (int k = 0; k < 8; ++k) dh[tid + 256 * k] = 0;
  __syncthreads();
  for (int i = tid; i < n; i += 256){
    u32 u = buf[base + i];
    int dl = (u >> 16) & 255, sg = (int)(u & 0xffffu) >> 13;
    atomicAdd(&dh[dl * 8 + sg], 1);
  }
  __syncthreads();
  int v8[8]; int tot = 0;
  #pragma unroll
  for (int s = 0; s < 8; ++s){ v8[s] = dh[tid * 8 + s]; tot += v8[s]; }
  sd[tid] = tot;
  __syncthreads();
  for (int o = 1; o < 256; o <<= 1){
    int t = (tid >= o) ? sd[tid - o] : 0;
    __syncthreads();
    sd[tid] += t;
    __syncthreads();
  }
  int excl = sd[tid] - tot;           // exclusive node prefix within bucket
  int run = base + excl;
  #pragma unroll
  for (int s = 0; s < 8; ++s){ dcur[tid * 8 + s] = run; run += v8[s]; }
  int d = (b << 8) + tid;
  if (d < NN){ offs[d] = base + excl; cnt[d] = tot; }
  __syncthreads();
  for (int i = tid; i < n; i += 256){
    u32 u = buf[base + i];
    int dl = (u >> 16) & 255, sg = (int)(u & 0xffffu) >> 13;
    int pos = atomicAdd(&dcur[dl * 8 + sg], 1);
    srcs[pos] = (u16)(u & 0xffffu);
  }
}

// per-node aggregation writing the result row to LDS. EXACT r1 proven body
// (2-chain, clean traffic). Do not touch.
__device__ void agg_node_lds(const u16* __restrict__ H, const float* __restrict__ Sv,
                             const float* __restrict__ Dv, const int* __restrict__ offs,
                             const int* __restrict__ cnt, const u16* __restrict__ srcs,
                             const float* __restrict__ bias, u16* __restrict__ xrow,
                             int do_relu, int wid, int lane, int* si, float* sw){
  int off = offs[wid], c = cnt[wid];
  float dvw = Dv[wid];
  float wself = __expf(fmaxf(Sv[wid] + dvw, 0.f));
  int cf = min(c, MAXD);
  int grp = lane >> 4, cg_ = lane & 15;
  const u32* H32 = (const u32*)H;
  union F8 { uint4 u; h2 p[4]; };
  // self row: issue load early so it overlaps the weight-gather latency
  F8 rself; rself.u = (uint4){0, 0, 0, 0};
  if (grp == 0) rself.u = *(const uint4*)(H32 + (size_t)wid * 64 + cg_ * 4);
  float dl = 0.f;
  for (int j = lane; j < c; j += 64){
    int sidx = (int)srcs[off + j];
    float wgt = __expf(fmaxf(Sv[sidx] + dvw, 0.f));
    if (j < MAXD){ si[j] = sidx; sw[j] = wgt; }
    dl += wgt;
  }
  float inv = 1.f / (wave_sum(dl) + wself);
  h2 accA[4] = {(h2){0,0},(h2){0,0},(h2){0,0},(h2){0,0}};
  h2 accB[4] = {(h2){0,0},(h2){0,0},(h2){0,0},(h2){0,0}};
  if (grp == 0){
    f16 wh = (f16)(wself * inv); h2 w2 = {wh, wh};
    #pragma unroll
    for (int i = 0; i < 4; ++i) accA[i] = rself.p[i] * w2;
  }
  // main loop: 8 edges/iter, two independent load+acc chains (2x MLP)
  int base = 0;
  int nfull = cf & ~7;
  for (; base < nfull; base += 8){
    int j0 = base + grp, j1 = j0 + 4;
    int s0 = si[j0], s1 = si[j1];
    float w0 = sw[j0] * inv, w1 = sw[j1] * inv;
    F8 r0; r0.u = *(const uint4*)(H32 + (size_t)s0 * 64 + cg_ * 4);
    F8 r1; r1.u = *(const uint4*)(H32 + (size_t)s1 * 64 + cg_ * 4);
    f16 wh0 = (f16)w0; h2 w20 = {wh0, wh0};
    f16 wh1 = (f16)w1; h2 w21 = {wh1, wh1};
    #pragma unroll
    for (int i = 0; i < 4; ++i){
      accA[i] += r0.p[i] * w20;
      accB[i] += r1.p[i] * w21;
    }
  }
  for (; base < cf; base += 4){
    int j = base + grp;
    float wgt = 0.f; int sidx = 0;
    if (j < cf){ wgt = sw[j] * inv; sidx = si[j]; }
    f16 wh = (f16)wgt; h2 w2 = {wh, wh};
    F8 r; r.u = *(const uint4*)(H32 + (size_t)sidx * 64 + cg_ * 4);
    #pragma unroll
    for (int i = 0; i < 4; ++i) accA[i] += r.p[i] * w2;
  }
  for (int base2 = MAXD; base2 < c; base2 += 4){   // ultra-rare tail
    int j = base2 + grp;
    bool valid = j < c;
    int sidx = valid ? (int)srcs[off + j] : 0;
    float wgt = valid ? __expf(fmaxf(Sv[sidx] + dvw, 0.f)) * inv : 0.f;
    f16 wh = (f16)wgt; h2 w2 = {wh, wh};
    F8 r; r.u = *(const uint4*)(H32 + (size_t)sidx * 64 + cg_ * 4);
    #pragma unroll
    for (int i = 0; i < 4; ++i) accA[i] += r.p[i] * w2;
  }
  #pragma unroll
  for (int i = 0; i < 4; ++i) accA[i] += accB[i];
  union FU { h2 v; float f; };
  #pragma unroll
  for (int i = 0; i < 4; ++i){
    FU a; a.v = accA[i];
    FU o1; o1.f = __shfl_xor(a.f, 16, 64); a.v = a.v + o1.v;
    FU o2; o2.f = __shfl_xor(a.f, 32, 64); a.v = a.v + o2.v;
    accA[i] = a.v;
  }
  if (grp == 0){
    uint4 pk;
    u32* pkp = (u32*)&pk;
    #pragma unroll
    for (int qq = 0; qq < 4; ++qq){
      float o0 = (float)accA[qq].x + bias[cg_ * 8 + 2 * qq];
      float o1 = (float)accA[qq].y + bias[cg_ * 8 + 2 * qq + 1];
      if (do_relu){ o0 = fmaxf(o0, 0.f); o1 = fmaxf(o1, 0.f); }
      pkp[qq] = ((u32)f2h(o1) << 16) | (u32)f2h(o0);
    }
    *(uint4*)(xrow + cg_ * 8) = pk;   // LDS row store (2-way banks: free)
  }
}

// kE: fused agg-layer1 (x1 rows -> LDS) + layer-2 GEMM + G2 projection.
// r10: reverted to the proven r8 structure (256 threads, 4 nodes/wave, 60 us).
__global__ __launch_bounds__(256, 8) void kE(const u16* __restrict__ Hbf1,
                                          const float* __restrict__ Sv1, const float* __restrict__ Dv1,
                                          const int* __restrict__ offs, const int* __restrict__ cnt,
                                          const u16* __restrict__ srcs, const float* __restrict__ b1,
                                          const u16* __restrict__ Wf2, const u16* __restrict__ Wfo,
                                          const float* __restrict__ as2, const float* __restrict__ ad2,
                                          u16* __restrict__ G2,
                                          float* __restrict__ Sv2, float* __restrict__ Dv2){
  __shared__ __align__(16) u16 Xs[16 * XST];
  __shared__ int   s_i[4][MAXD];
  __shared__ float s_w[4][MAXD];
  __shared__ float svp[16], dvp[16];
  int tid = threadIdx.x, wv = tid >> 6, lane = tid & 63;
  int rtile = blockIdx.x;
  if (tid < 16){ svp[tid] = 0.f; dvp[tid] = 0.f; }
  #pragma unroll
  for (int k = 0; k < 4; ++k){
    int r = wv * 4 + k;
    agg_node_lds(Hbf1, Sv1, Dv1, offs, cnt, srcs, b1, Xs + r * XST, 1,
                 rtile * 16 + r, lane, s_i[wv], s_w[wv]);
  }
  __syncthreads();
  // GEMM 1: h2 cols t = 2wv, 2wv+1 from Wf2 (32 KB, L2-resident broadcast)
  const uint4* Wg = (const uint4*)Wf2;
  int q = lane >> 4, n = lane & 15;
  f32x4 acc[2] = {(f32x4){0.f,0.f,0.f,0.f}, (f32x4){0.f,0.f,0.f,0.f}};
  union F8 { uint4 u; f16x8 v; };
  #pragma unroll
  for (int ks = 0; ks < 4; ++ks){
    F8 a; a.u = *(const uint4*)((const char*)Xs + n * (XST * 2) + ks * 64 + q * 16);
    #pragma unroll
    for (int tt = 0; tt < 2; ++tt){
      F8 b; b.u = Wg[(ks * 8 + wv * 2 + tt) * 64 + lane];
      acc[tt] = __builtin_amdgcn_mfma_f32_16x16x32_f16(a.v, b.v, acc[tt], 0, 0, 0);
    }
  }
  float ps[4] = {0, 0, 0, 0}, pd[4] = {0, 0, 0, 0};
  #pragma unroll
  for (int tt = 0; tt < 2; ++tt){
    int t = wv * 2 + tt;
    float a_s = as2[t * 16 + n];
    float a_d = ad2[t * 16 + n];
    #pragma unroll
    for (int rg = 0; rg < 4; ++rg){
      ps[rg] += acc[tt][rg] * a_s;
      pd[rg] += acc[tt][rg] * a_d;
    }
  }
  #pragma unroll
  for (int rg = 0; rg < 4; ++rg){
    #pragma unroll
    for (int s = 1; s < 16; s <<= 1){
      ps[rg] += __shfl_xor(ps[rg], s, 64);
      pd[rg] += __shfl_xor(pd[rg], s, 64);
    }
  }
  if (n == 0){
    #pragma unroll
    for (int rg = 0; rg < 4; ++rg){
      atomicAdd(&svp[q * 4 + rg], ps[rg]);
      atomicAdd(&dvp[q * 4 + rg], pd[rg]);
    }
  }
  __syncthreads();   // all waves done reading Xs (GEMM 1 A-frags) + svp final
  if (tid < 16){ Sv2[rtile * 16 + tid] = svp[tid]; Dv2[rtile * 16 + tid] = dvp[tid]; }
  // stage h2 tile into Xs (row = q*4+rg, col = (2wv+tt)*16+n)
  #pragma unroll
  for (int tt = 0; tt < 2; ++tt)
    #pragma unroll
    for (int rg = 0; rg < 4; ++rg)
      Xs[(q * 4 + rg) * XST + (wv * 2 + tt) * 16 + n] = f2h(acc[tt][rg]);
  __syncthreads();
  // GEMM 2: G2 = h2 @ Wout, wave wv -> output cols wv*16..+16 (Wfo nct=4)
  const uint4* Wo4 = (const uint4*)Wfo;
  f32x4 g = (f32x4){0.f, 0.f, 0.f, 0.f};
  #pragma unroll
  for (int ks = 0; ks < 4; ++ks){
    F8 a; a.u = *(const uint4*)((const char*)Xs + n * (XST * 2) + ks * 64 + q * 16);
    F8 b; b.u = Wo4[(ks * 4 + wv) * 64 + lane];
    g = __builtin_amdgcn_mfma_f32_16x16x32_f16(a.v, b.v, g, 0, 0, 0);
  }
  #pragma unroll
  for (int rg = 0; rg < 4; ++rg){
    int grow = rtile * 16 + q * 4 + rg;
    G2[(size_t)grow * DYY + wv * 16 + n] = f2h(g[rg]);
  }
}

// agg_node_out: layer-2 aggregation directly in projected space — gathers
// 128-B G2 rows and writes the final fp32 out row (+ c64 const). r8 body:
// 8-lane groups x uint4, 16 edges in flight per iteration.
__device__ void agg_node_out(const u16* __restrict__ G2v, const float* __restrict__ Sv,
                             const float* __restrict__ Dv, const int* __restrict__ offs,
                             const int* __restrict__ cnt, const u16* __restrict__ srcs,
                             const float* __restrict__ c64, float* __restrict__ out,
                             int wid, int lane, int* si, float* sw){
  int off = offs[wid], c = cnt[wid];
  float dvw = Dv[wid];
  float wself = __expf(fmaxf(Sv[wid] + dvw, 0.f));
  int cf = min(c, MAXD);
  int grp = lane >> 3, cg_ = lane & 7;   // 8 groups x 8 lanes; lane covers 16 B
  const u32* G = (const u32*)G2v;        // row stride 32 u32 (64 fp16)
  union F8 { uint4 u; h2 p[4]; };
  F8 rself; rself.u = (uint4){0, 0, 0, 0};
  if (grp == 0) rself.u = *(const uint4*)(G + (size_t)wid * 32 + cg_ * 4);
  float dl = 0.f;
  for (int j = lane; j < c; j += 64){
    int sidx = (int)srcs[off + j];
    float wgt = __expf(fmaxf(Sv[sidx] + dvw, 0.f));
    if (j < MAXD){ si[j] = sidx; sw[j] = wgt; }
    dl += wgt;
  }
  float inv = 1.f / (wave_sum(dl) + wself);
  h2 accA[4] = {(h2){0,0},(h2){0,0},(h2){0,0},(h2){0,0}};
  h2 accB[4] = {(h2){0,0},(h2){0,0},(h2){0,0},(h2){0,0}};
  if (grp == 0){
    f16 wh = (f16)(wself * inv); h2 w2 = {wh, wh};
    #pragma unroll
    for (int i = 0; i < 4; ++i) accA[i] = rself.p[i] * w2;
  }
  // main loop: 16 edges/iter, two independent load+acc chains per group
  int base = 0;
  int nfull = cf & ~15;
  for (; base < nfull; base += 16){
    int j0 = base + grp, j1 = j0 + 8;
    int s0 = si[j0], s1 = si[j1];
    float w0 = sw[j0] * inv, w1 = sw[j1] * inv;
    F8 r0; r0.u = *(const uint4*)(G + (size_t)s0 * 32 + cg_ * 4);
    F8 r1; r1.u = *(const uint4*)(G + (size_t)s1 * 32 + cg_ * 4);
    f16 wh0 = (f16)w0; h2 x0 = {wh0, wh0};
    f16 wh1 = (f16)w1; h2 x1 = {wh1, wh1};
    #pragma unroll
    for (int i = 0; i < 4; ++i){
      accA[i] += r0.p[i] * x0;
      accB[i] += r1.p[i] * x1;
    }
  }
  for (; base < cf; base += 8){
    int j = base + grp;
    float wgt = 0.f; int sidx = 0;
    if (j < cf){ wgt = sw[j] * inv; sidx = si[j]; }
    f16 wh = (f16)wgt; h2 w2 = {wh, wh};
    F8 r; r.u = *(const uint4*)(G + (size_t)sidx * 32 + cg_ * 4);
    #pragma unroll
    for (int i = 0; i < 4; ++i) accA[i] += r.p[i] * w2;
  }
  for (int b2i = MAXD; b2i < c; b2i += 8){   // ultra-rare tail (deg > MAXD)
    int j = b2i + grp;
    bool valid = j < c;
    int sidx = valid ? (int)srcs[off + j] : 0;
    float wgt = valid ? __expf(fmaxf(Sv[sidx] + dvw, 0.f)) * inv : 0.f;
    F8 r; r.u = *(const uint4*)(G + (size_t)sidx * 32 + cg_ * 4);
    f16 wh = (f16)wgt; h2 w2 = {wh, wh};
    #pragma unroll
    for (int i = 0; i < 4; ++i) accA[i] += r.p[i] * w2;
  }
  #pragma unroll
  for (int i = 0; i < 4; ++i) accA[i] += accB[i];
  union FU { h2 v; float f; };
  #pragma unroll
  for (int i = 0; i < 4; ++i){
    FU a; a.v = accA[i];
    FU o1; o1.f = __shfl_xor(a.f,  8, 64); a.v = a.v + o1.v;
    FU o2; o2.f = __shfl_xor(a.f, 16, 64); a.v = a.v + o2.v;
    FU o3; o3.f = __shfl_xor(a.f, 32, 64); a.v = a.v + o3.v;
    accA[i] = a.v;
  }
  if (grp == 0){
    // lane cg_ holds out[cg_*8 .. +8): 4x h2 -> 8 fp32 + c64
    float4 o0, o1v;
    const float4* cv = (const float4*)(c64 + cg_ * 8);
    o0.x = (float)accA[0].x + cv[0].x;
    o0.y = (float)accA[0].y + cv[0].y;
    o0.z = (float)accA[1].x + cv[0].z;
    o0.w = (float)accA[1].y + cv[0].w;
    o1v.x = (float)accA[2].x + cv[1].x;
    o1v.y = (float)accA[2].y + cv[1].y;
    o1v.z = (float)accA[3].x + cv[1].z;
    o1v.w = (float)accA[3].y + cv[1].w;
    float4* op = (float4*)(out + (size_t)wid * DYY + cg_ * 8);
    op[0] = o0; op[1] = o1v;
  }
}

// kF: layer-2 aggregation in projected space. ONE node per wave
// (grid NN/4, 4 waves/block) — r9 form, kept (saved ~2.4 us vs 4/wave).
__global__ __launch_bounds__(256, 8) void kF(const u16* __restrict__ G2,
                                          const float* __restrict__ Sv2, const float* __restrict__ Dv2,
                                          const int* __restrict__ offs, const int* __restrict__ cnt,
                                          const u16* __restrict__ srcs,
                                          const float* __restrict__ c64,
                                          float* __restrict__ out){
  __shared__ int   s_i[4][MAXD];
  __shared__ float s_w[4][MAXD];
  int tid = threadIdx.x, wv = tid >> 6, lane = tid & 63;
  agg_node_out(G2, Sv2, Dv2, offs, cnt, srcs, c64, out,
               blockIdx.x * 4 + wv, lane, s_i[wv], s_w[wv]);
}

extern "C" void kernel_launch(void* const* d_in, const int* in_sizes, int n_in,
                              void* d_out, int out_size, void* d_ws, size_t ws_size,
                              hipStream_t stream) {
  const float* node_x = (const float*)d_in[0];
  const int* ei   = (const int*)d_in[1];
  const int* srcp = ei;
  const int* dstp = ei + EE;
  const float* W1  = (const float*)d_in[2];
  const float* as1 = (const float*)d_in[3];
  const float* ad1 = (const float*)d_in[4];
  const float* b1  = (const float*)d_in[5];
  const float* W2  = (const float*)d_in[6];
  const float* as2 = (const float*)d_in[7];
  const float* ad2 = (const float*)d_in[8];
  const float* b2  = (const float*)d_in[9];
  const float* Wo  = (const float*)d_in[10];
  const float* bo  = (const float*)d_in[11];

  // workspace carve: ~28 MB. buf (6.4 MB) aliases G2 (6.4 MB exactly):
  // buf dead after kD; kE writes G2.
  char* w = (char*)d_ws;
  u16*   Hbf1  = (u16*)w;  w += (size_t)NN * DD * 2;  // 12.8 MB layer-1 h (fp16)
  u32*   buf   = (u32*)w;
  u16*   G2    = (u16*)w;  w += (size_t)EE * 4;       // 6.4 MB (= NN*DYY*2)
  float* Sv1   = (float*)w; w += (size_t)NN * 4;
  float* Dv1   = (float*)w; w += (size_t)NN * 4;
  float* Sv2   = (float*)w; w += (size_t)NN * 4;
  float* Dv2   = (float*)w; w += (size_t)NN * 4;
  int*   cnt   = (int*)w;   w += (size_t)NN * 4;
  int*   offs  = (int*)w;   w += (size_t)NN * 4;
  int*   btot  = (int*)w;   w += 1024;
  int*   bbase = (int*)w;   w += 1024;
  int*   hist2d = (int*)w;  w += GB * 256 * 4;        // 200 KB
  u16*   srcs  = (u16*)w;   w += (size_t)EE * 2;      // 3.2 MB
  u16*   Wf1   = (u16*)w;   w += 32768;
  u16*   Wf2   = (u16*)w;   w += 32768;
  u16*   Wfo   = (u16*)w;   w += 16384;
  float* c64   = (float*)w; w += 256;

  const int TB = 256;

  kA_prep    <<<217,      TB, 0, stream>>>(dstp, hist2d, W1, W2, Wo, b2, bo,
                                           Wf1, Wf2, Wfo, c64);
  kBC        <<<GB + GMM, TB, 0, stream>>>(srcp, dstp, hist2d, btot, bbase, buf,
                                           node_x, Wf1, Hbf1, as1, ad1, Sv1, Dv1);
  kD_finalize<<<NB,       TB, 0, stream>>>(buf, btot, bbase, offs, cnt, srcs);
  kE         <<<NTILE,    TB, 0, stream>>>(Hbf1, Sv1, Dv1, offs, cnt, srcs, b1,
                                           Wf2, Wfo, as2, ad2, G2, Sv2, Dv2);
  kF         <<<NFB,      TB, 0, stream>>>(G2, Sv2, Dv2, offs, cnt, srcs, c64,
                                           (float*)d_out);
}

// Round 11
// 238.084 us; speedup vs baseline: 1.0213x; 1.0125x over previous
//
#include <hip/hip_runtime.h>
#include <hip/hip_fp16.h>

typedef unsigned short u16;
typedef unsigned int   u32;
typedef _Float16 f16;
typedef __attribute__((ext_vector_type(8))) f16 f16x8;
typedef __attribute__((ext_vector_type(2))) f16 h2;
typedef __attribute__((ext_vector_type(4))) float f32x4;

#define NN 50000
#define EE 1600000
#define DD 128
#define DYY 64
#define NB 196      // dst buckets: dst>>8
#define EPB 8192    // edges per bucketing chunk
#define GB 196      // ceil(EE/EPB)
#define MAXD 160    // per-wave LDS edge cache
#define NTILE 3125  // 50000/16 row tiles (exact)
#define NFB 12500   // kF blocks: 50000/4 (1 node per wave)
#define GMM 782     // ceil(NTILE/4)
#define XST 144     // LDS x-tile row stride in u16 (288 B: 16B-aligned, ~4-way max)

__device__ __forceinline__ u16 f2h(float f){
  union { f16 h; u16 u; } x; x.h = (f16)f; return x.u;
}
__device__ __forceinline__ float wave_sum(float v){
  #pragma unroll
  for (int s = 32; s; s >>= 1) v += __shfl_xor(v, s, 64);
  return v;
}

// fp32 W[K=128][N=nct*16] -> fp16 MFMA B-fragment layout:
// slot s=(ks*nct+t)*64+lane holds W[ks*32+(lane>>4)*8+j][t*16+(lane&15)], j=0..7
__device__ __forceinline__ void wfrag_one(const float* __restrict__ W, u16* __restrict__ Wf,
                                          int nct, int s){
  int lane = s & 63;
  int t  = (s >> 6) % nct;
  int ks = (s >> 6) / nct;
  int q = lane >> 4, n = lane & 15;
  int N = nct * 16;
  u16 tmp[8];
  #pragma unroll
  for (int j = 0; j < 8; ++j)
    tmp[j] = f2h(W[(ks * 32 + q * 8 + j) * N + t * 16 + n]);
  *(uint4*)(Wf + (size_t)s * 8) = *(const uint4*)tmp;
}

// launch A: blocks 0..195 per-chunk dst-bucket histograms; 196..203 W1 frags;
// 204..211 W2; 212..215 Wout; 216: c64 = b2 @ Wout + b_out (fp32, 64 vals).
__global__ __launch_bounds__(256) void kA_prep(const int* __restrict__ dst, int* __restrict__ hist2d,
                                               const float* __restrict__ W1, const float* __restrict__ W2,
                                               const float* __restrict__ Wo,
                                               const float* __restrict__ b2, const float* __restrict__ bo,
                                               u16* __restrict__ Wf1, u16* __restrict__ Wf2,
                                               u16* __restrict__ Wfo, float* __restrict__ c64){
  int b = blockIdx.x, tid = threadIdx.x;
  if (b < GB){
    __shared__ int hist[256];
    hist[tid] = 0;
    __syncthreads();
    int e0 = b * EPB, e1 = min(e0 + EPB, EE);
    for (int e = e0 + tid; e < e1; e += 256) atomicAdd(&hist[dst[e] >> 8], 1);
    __syncthreads();
    hist2d[b * 256 + tid] = hist[tid];
  } else if (b < 204) wfrag_one(W1, Wf1, 8, (b - 196) * 256 + tid);
  else if (b < 212)   wfrag_one(W2, Wf2, 8, (b - 204) * 256 + tid);
  else if (b < 216)   wfrag_one(Wo, Wfo, 4, (b - 212) * 256 + tid);
  else if (tid < DYY){
    float s = bo[tid];
    for (int k = 0; k < DD; ++k) s += b2[k] * Wo[k * DYY + tid];
    c64[tid] = s;
  }
}

// full-tile-per-wave MFMA GEMM (layer 1, fp32 X): stages W frags into Wl,
// 4 row-tiles/block (one per wave), fused Sv/Dv epilogue.
__device__ __forceinline__ void gemm_tile(const float* __restrict__ X,
                                          const u16* __restrict__ Wf, u16* __restrict__ Hout,
                                          const float* __restrict__ as, const float* __restrict__ ad,
                                          float* __restrict__ Sv, float* __restrict__ Dv,
                                          int blk, int tid, uint4* Wl){
  const uint4* Wg = (const uint4*)Wf;
  #pragma unroll
  for (int i = 0; i < 8; ++i) Wl[tid + 256 * i] = Wg[tid + 256 * i];
  __syncthreads();
  int wv = tid >> 6, lane = tid & 63;
  int rtile = blk * 4 + wv;
  if (rtile >= NTILE) return;
  int q = lane >> 4, n = lane & 15;
  int arow = rtile * 16 + n;
  f32x4 acc[8];
  #pragma unroll
  for (int t = 0; t < 8; ++t) acc[t] = (f32x4){0.f, 0.f, 0.f, 0.f};
  union F8 { uint4 u; f16x8 v; f16 h[8]; };
  #pragma unroll
  for (int ks = 0; ks < 4; ++ks){
    int kb = ks * 32 + q * 8;
    const float* xp = X + (size_t)arow * DD + kb;
    float4 f0 = *(const float4*)xp;
    float4 f1 = *(const float4*)(xp + 4);
    F8 a;
    a.h[0] = (f16)f0.x; a.h[1] = (f16)f0.y; a.h[2] = (f16)f0.z; a.h[3] = (f16)f0.w;
    a.h[4] = (f16)f1.x; a.h[5] = (f16)f1.y; a.h[6] = (f16)f1.z; a.h[7] = (f16)f1.w;
    #pragma unroll
    for (int t = 0; t < 8; ++t){
      F8 b; b.u = Wl[(ks * 8 + t) * 64 + lane];
      acc[t] = __builtin_amdgcn_mfma_f32_16x16x32_f16(a.v, b.v, acc[t], 0, 0, 0);
    }
  }
  float ps[4] = {0, 0, 0, 0}, pd[4] = {0, 0, 0, 0};
  #pragma unroll
  for (int t = 0; t < 8; ++t){
    float a_s = as[t * 16 + n];
    float a_d = ad[t * 16 + n];
    #pragma unroll
    for (int rg = 0; rg < 4; ++rg){
      ps[rg] += acc[t][rg] * a_s;
      pd[rg] += acc[t][rg] * a_d;
    }
  }
  #pragma unroll
  for (int rg = 0; rg < 4; ++rg){
    #pragma unroll
    for (int s = 1; s < 16; s <<= 1){
      ps[rg] += __shfl_xor(ps[rg], s, 64);
      pd[rg] += __shfl_xor(pd[rg], s, 64);
    }
  }
  #pragma unroll
  for (int rg = 0; rg < 4; ++rg){
    int grow = rtile * 16 + q * 4 + rg;
    if (n == 0){ Sv[grow] = ps[rg]; Dv[grow] = pd[rg]; }
    #pragma unroll
    for (int t = 0; t < 8; ++t)
      Hout[(size_t)grow * DD + t * 16 + n] = f2h(acc[t][rg]);
  }
}

// launch BC (fused; both halves depend only on kA):
//   blocks 0..195: per-chunk bucket scan + scatter into bucket-contiguous buf
//   blocks 196..977: layer-1 GEMM tiles (fp32 X) -> Hbf1, Sv1, Dv1
__global__ __launch_bounds__(256) void kBC(const int* __restrict__ src, const int* __restrict__ dst,
                                           const int* __restrict__ hist2d,
                                           int* __restrict__ btot, int* __restrict__ bbase,
                                           u32* __restrict__ buf,
                                           const float* __restrict__ X0, const u16* __restrict__ Wf1,
                                           u16* __restrict__ Hbf1,
                                           const float* __restrict__ as1, const float* __restrict__ ad1,
                                           float* __restrict__ Sv1, float* __restrict__ Dv1){
  __shared__ __align__(16) uint4 Wl[2048];
  int b = blockIdx.x, tid = threadIdx.x;
  if (b < GB){
    int* lcur = (int*)Wl;
    int* sd   = ((int*)Wl) + 256;
    int c = b;
    int pre = 0, tot = 0;
    for (int cc = 0; cc < GB; ++cc){
      int v = hist2d[cc * 256 + tid];
      if (cc < c) pre += v;
      tot += v;
    }
    sd[tid] = tot;
    __syncthreads();
    for (int o = 1; o < 256; o <<= 1){
      int t = (tid >= o) ? sd[tid - o] : 0;
      __syncthreads();
      sd[tid] += t;
      __syncthreads();
    }
    int bb = sd[tid] - tot;
    if (c == 0){ btot[tid] = tot; bbase[tid] = bb; }
    lcur[tid] = bb + pre;
    __syncthreads();
    int e0 = c * EPB, e1 = min(e0 + EPB, EE);
    for (int e = e0 + tid; e < e1; e += 256){
      int d = dst[e];
      int pos = atomicAdd(&lcur[d >> 8], 1);
      buf[pos] = (u32)src[e] | ((u32)(d & 255) << 16);
    }
  } else {
    gemm_tile(X0, Wf1, Hbf1, as1, ad1, Sv1, Dv1, b - GB, tid, Wl);
  }
}

// launch D: per-bucket finalize -> offs/cnt/srcs. Simple 256-counter counting
// sort (r11: reverted from the r10 (dst,seg) sort — seg-order produced ZERO
// FETCH reduction in kE: the ~156 MB is compulsory cross-XCD traffic for a
// random graph, so the extra sort pass was pure overhead).
__global__ __launch_bounds__(256) void kD_finalize(const u32* __restrict__ buf,
                                                   const int* __restrict__ btot, const int* __restrict__ bbase,
                                                   int* __restrict__ offs, int* __restrict__ cnt,
                                                   u16* __restrict__ srcs){
  __shared__ int dh[256];
  __shared__ int sd[256];
  __shared__ int dcur[256];
  int tid = threadIdx.x, b = blockIdx.x;
  int n = btot[b], base = bbase[b];
  dh[tid] = 0;
  __syncthreads();
  for (int i = tid; i < n; i += 256) atomicAdd(&dh[(buf[base + i] >> 16) & 255], 1);
  __syncthreads();
  int v = dh[tid];
  sd[tid] = v;
  __syncthreads();
  for (int o = 1; o < 256; o <<= 1){
    int t = (tid >= o) ? sd[tid - o] : 0;
    __syncthreads();
    sd[tid] += t;
    __syncthreads();
  }
  int excl = sd[tid] - v;
  dcur[tid] = base + excl;
  int d = (b << 8) + tid;
  if (d < NN){ offs[d] = base + excl; cnt[d] = v; }
  __syncthreads();
  for (int i = tid; i < n; i += 256){
    u32 u = buf[base + i];
    int pos = atomicAdd(&dcur[(u >> 16) & 255], 1);
    srcs[pos] = (u16)(u & 0xffffu);
  }
}

// per-node aggregation writing the result row to LDS. EXACT r1 proven body
// (2-chain, clean traffic). Do not touch.
__device__ void agg_node_lds(const u16* __restrict__ H, const float* __restrict__ Sv,
                             const float* __restrict__ Dv, const int* __restrict__ offs,
                             const int* __restrict__ cnt, const u16* __restrict__ srcs,
                             const float* __restrict__ bias, u16* __restrict__ xrow,
                             int do_relu, int wid, int lane, int* si, float* sw){
  int off = offs[wid], c = cnt[wid];
  float dvw = Dv[wid];
  float wself = __expf(fmaxf(Sv[wid] + dvw, 0.f));
  int cf = min(c, MAXD);
  int grp = lane >> 4, cg_ = lane & 15;
  const u32* H32 = (const u32*)H;
  union F8 { uint4 u; h2 p[4]; };
  // self row: issue load early so it overlaps the weight-gather latency
  F8 rself; rself.u = (uint4){0, 0, 0, 0};
  if (grp == 0) rself.u = *(const uint4*)(H32 + (size_t)wid * 64 + cg_ * 4);
  float dl = 0.f;
  for (int j = lane; j < c; j += 64){
    int sidx = (int)srcs[off + j];
    float wgt = __expf(fmaxf(Sv[sidx] + dvw, 0.f));
    if (j < MAXD){ si[j] = sidx; sw[j] = wgt; }
    dl += wgt;
  }
  float inv = 1.f / (wave_sum(dl) + wself);
  h2 accA[4] = {(h2){0,0},(h2){0,0},(h2){0,0},(h2){0,0}};
  h2 accB[4] = {(h2){0,0},(h2){0,0},(h2){0,0},(h2){0,0}};
  if (grp == 0){
    f16 wh = (f16)(wself * inv); h2 w2 = {wh, wh};
    #pragma unroll
    for (int i = 0; i < 4; ++i) accA[i] = rself.p[i] * w2;
  }
  // main loop: 8 edges/iter, two independent load+acc chains (2x MLP)
  int base = 0;
  int nfull = cf & ~7;
  for (; base < nfull; base += 8){
    int j0 = base + grp, j1 = j0 + 4;
    int s0 = si[j0], s1 = si[j1];
    float w0 = sw[j0] * inv, w1 = sw[j1] * inv;
    F8 r0; r0.u = *(const uint4*)(H32 + (size_t)s0 * 64 + cg_ * 4);
    F8 r1; r1.u = *(const uint4*)(H32 + (size_t)s1 * 64 + cg_ * 4);
    f16 wh0 = (f16)w0; h2 w20 = {wh0, wh0};
    f16 wh1 = (f16)w1; h2 w21 = {wh1, wh1};
    #pragma unroll
    for (int i = 0; i < 4; ++i){
      accA[i] += r0.p[i] * w20;
      accB[i] += r1.p[i] * w21;
    }
  }
  for (; base < cf; base += 4){
    int j = base + grp;
    float wgt = 0.f; int sidx = 0;
    if (j < cf){ wgt = sw[j] * inv; sidx = si[j]; }
    f16 wh = (f16)wgt; h2 w2 = {wh, wh};
    F8 r; r.u = *(const uint4*)(H32 + (size_t)sidx * 64 + cg_ * 4);
    #pragma unroll
    for (int i = 0; i < 4; ++i) accA[i] += r.p[i] * w2;
  }
  for (int base2 = MAXD; base2 < c; base2 += 4){   // ultra-rare tail
    int j = base2 + grp;
    bool valid = j < c;
    int sidx = valid ? (int)srcs[off + j] : 0;
    float wgt = valid ? __expf(fmaxf(Sv[sidx] + dvw, 0.f)) * inv : 0.f;
    f16 wh = (f16)wgt; h2 w2 = {wh, wh};
    F8 r; r.u = *(const uint4*)(H32 + (size_t)sidx * 64 + cg_ * 4);
    #pragma unroll
    for (int i = 0; i < 4; ++i) accA[i] += r.p[i] * w2;
  }
  #pragma unroll
  for (int i = 0; i < 4; ++i) accA[i] += accB[i];
  union FU { h2 v; float f; };
  #pragma unroll
  for (int i = 0; i < 4; ++i){
    FU a; a.v = accA[i];
    FU o1; o1.f = __shfl_xor(a.f, 16, 64); a.v = a.v + o1.v;
    FU o2; o2.f = __shfl_xor(a.f, 32, 64); a.v = a.v + o2.v;
    accA[i] = a.v;
  }
  if (grp == 0){
    uint4 pk;
    u32* pkp = (u32*)&pk;
    #pragma unroll
    for (int qq = 0; qq < 4; ++qq){
      float o0 = (float)accA[qq].x + bias[cg_ * 8 + 2 * qq];
      float o1 = (float)accA[qq].y + bias[cg_ * 8 + 2 * qq + 1];
      if (do_relu){ o0 = fmaxf(o0, 0.f); o1 = fmaxf(o1, 0.f); }
      pkp[qq] = ((u32)f2h(o1) << 16) | (u32)f2h(o0);
    }
    *(uint4*)(xrow + cg_ * 8) = pk;   // LDS row store (2-way banks: free)
  }
}

// kE: fused agg-layer1 (x1 rows -> LDS) + layer-2 GEMM + G2 projection.
// Proven r8 structure (256 threads, 4 nodes/wave, 60 us, clean counters).
__global__ __launch_bounds__(256, 8) void kE(const u16* __restrict__ Hbf1,
                                          const float* __restrict__ Sv1, const float* __restrict__ Dv1,
                                          const int* __restrict__ offs, const int* __restrict__ cnt,
                                          const u16* __restrict__ srcs, const float* __restrict__ b1,
                                          const u16* __restrict__ Wf2, const u16* __restrict__ Wfo,
                                          const float* __restrict__ as2, const float* __restrict__ ad2,
                                          u16* __restrict__ G2,
                                          float* __restrict__ Sv2, float* __restrict__ Dv2){
  __shared__ __align__(16) u16 Xs[16 * XST];
  __shared__ int   s_i[4][MAXD];
  __shared__ float s_w[4][MAXD];
  __shared__ float svp[16], dvp[16];
  int tid = threadIdx.x, wv = tid >> 6, lane = tid & 63;
  int rtile = blockIdx.x;
  if (tid < 16){ svp[tid] = 0.f; dvp[tid] = 0.f; }
  #pragma unroll
  for (int k = 0; k < 4; ++k){
    int r = wv * 4 + k;
    agg_node_lds(Hbf1, Sv1, Dv1, offs, cnt, srcs, b1, Xs + r * XST, 1,
                 rtile * 16 + r, lane, s_i[wv], s_w[wv]);
  }
  __syncthreads();
  // GEMM 1: h2 cols t = 2wv, 2wv+1 from Wf2 (32 KB, L2-resident broadcast)
  const uint4* Wg = (const uint4*)Wf2;
  int q = lane >> 4, n = lane & 15;
  f32x4 acc[2] = {(f32x4){0.f,0.f,0.f,0.f}, (f32x4){0.f,0.f,0.f,0.f}};
  union F8 { uint4 u; f16x8 v; };
  #pragma unroll
  for (int ks = 0; ks < 4; ++ks){
    F8 a; a.u = *(const uint4*)((const char*)Xs + n * (XST * 2) + ks * 64 + q * 16);
    #pragma unroll
    for (int tt = 0; tt < 2; ++tt){
      F8 b; b.u = Wg[(ks * 8 + wv * 2 + tt) * 64 + lane];
      acc[tt] = __builtin_amdgcn_mfma_f32_16x16x32_f16(a.v, b.v, acc[tt], 0, 0, 0);
    }
  }
  float ps[4] = {0, 0, 0, 0}, pd[4] = {0, 0, 0, 0};
  #pragma unroll
  for (int tt = 0; tt < 2; ++tt){
    int t = wv * 2 + tt;
    float a_s = as2[t * 16 + n];
    float a_d = ad2[t * 16 + n];
    #pragma unroll
    for (int rg = 0; rg < 4; ++rg){
      ps[rg] += acc[tt][rg] * a_s;
      pd[rg] += acc[tt][rg] * a_d;
    }
  }
  #pragma unroll
  for (int rg = 0; rg < 4; ++rg){
    #pragma unroll
    for (int s = 1; s < 16; s <<= 1){
      ps[rg] += __shfl_xor(ps[rg], s, 64);
      pd[rg] += __shfl_xor(pd[rg], s, 64);
    }
  }
  if (n == 0){
    #pragma unroll
    for (int rg = 0; rg < 4; ++rg){
      atomicAdd(&svp[q * 4 + rg], ps[rg]);
      atomicAdd(&dvp[q * 4 + rg], pd[rg]);
    }
  }
  __syncthreads();   // all waves done reading Xs (GEMM 1 A-frags) + svp final
  if (tid < 16){ Sv2[rtile * 16 + tid] = svp[tid]; Dv2[rtile * 16 + tid] = dvp[tid]; }
  // stage h2 tile into Xs (row = q*4+rg, col = (2wv+tt)*16+n)
  #pragma unroll
  for (int tt = 0; tt < 2; ++tt)
    #pragma unroll
    for (int rg = 0; rg < 4; ++rg)
      Xs[(q * 4 + rg) * XST + (wv * 2 + tt) * 16 + n] = f2h(acc[tt][rg]);
  __syncthreads();
  // GEMM 2: G2 = h2 @ Wout, wave wv -> output cols wv*16..+16 (Wfo nct=4)
  const uint4* Wo4 = (const uint4*)Wfo;
  f32x4 g = (f32x4){0.f, 0.f, 0.f, 0.f};
  #pragma unroll
  for (int ks = 0; ks < 4; ++ks){
    F8 a; a.u = *(const uint4*)((const char*)Xs + n * (XST * 2) + ks * 64 + q * 16);
    F8 b; b.u = Wo4[(ks * 4 + wv) * 64 + lane];
    g = __builtin_amdgcn_mfma_f32_16x16x32_f16(a.v, b.v, g, 0, 0, 0);
  }
  #pragma unroll
  for (int rg = 0; rg < 4; ++rg){
    int grow = rtile * 16 + q * 4 + rg;
    G2[(size_t)grow * DYY + wv * 16 + n] = f2h(g[rg]);
  }
}

// agg_node_out: layer-2 aggregation directly in projected space — gathers
// 128-B G2 rows and writes the final fp32 out row (+ c64 const). r8 body:
// 8-lane groups x uint4, 16 edges in flight per iteration.
__device__ void agg_node_out(const u16* __restrict__ G2v, const float* __restrict__ Sv,
                             const float* __restrict__ Dv, const int* __restrict__ offs,
                             const int* __restrict__ cnt, const u16* __restrict__ srcs,
                             const float* __restrict__ c64, float* __restrict__ out,
                             int wid, int lane, int* si, float* sw){
  int off = offs[wid], c = cnt[wid];
  float dvw = Dv[wid];
  float wself = __expf(fmaxf(Sv[wid] + dvw, 0.f));
  int cf = min(c, MAXD);
  int grp = lane >> 3, cg_ = lane & 7;   // 8 groups x 8 lanes; lane covers 16 B
  const u32* G = (const u32*)G2v;        // row stride 32 u32 (64 fp16)
  union F8 { uint4 u; h2 p[4]; };
  F8 rself; rself.u = (uint4){0, 0, 0, 0};
  if (grp == 0) rself.u = *(const uint4*)(G + (size_t)wid * 32 + cg_ * 4);
  float dl = 0.f;
  for (int j = lane; j < c; j += 64){
    int sidx = (int)srcs[off + j];
    float wgt = __expf(fmaxf(Sv[sidx] + dvw, 0.f));
    if (j < MAXD){ si[j] = sidx; sw[j] = wgt; }
    dl += wgt;
  }
  float inv = 1.f / (wave_sum(dl) + wself);
  h2 accA[4] = {(h2){0,0},(h2){0,0},(h2){0,0},(h2){0,0}};
  h2 accB[4] = {(h2){0,0},(h2){0,0},(h2){0,0},(h2){0,0}};
  if (grp == 0){
    f16 wh = (f16)(wself * inv); h2 w2 = {wh, wh};
    #pragma unroll
    for (int i = 0; i < 4; ++i) accA[i] = rself.p[i] * w2;
  }
  // main loop: 16 edges/iter, two independent load+acc chains per group
  int base = 0;
  int nfull = cf & ~15;
  for (; base < nfull; base += 16){
    int j0 = base + grp, j1 = j0 + 8;
    int s0 = si[j0], s1 = si[j1];
    float w0 = sw[j0] * inv, w1 = sw[j1] * inv;
    F8 r0; r0.u = *(const uint4*)(G + (size_t)s0 * 32 + cg_ * 4);
    F8 r1; r1.u = *(const uint4*)(G + (size_t)s1 * 32 + cg_ * 4);
    f16 wh0 = (f16)w0; h2 x0 = {wh0, wh0};
    f16 wh1 = (f16)w1; h2 x1 = {wh1, wh1};
    #pragma unroll
    for (int i = 0; i < 4; ++i){
      accA[i] += r0.p[i] * x0;
      accB[i] += r1.p[i] * x1;
    }
  }
  for (; base < cf; base += 8){
    int j = base + grp;
    float wgt = 0.f; int sidx = 0;
    if (j < cf){ wgt = sw[j] * inv; sidx = si[j]; }
    f16 wh = (f16)wgt; h2 w2 = {wh, wh};
    F8 r; r.u = *(const uint4*)(G + (size_t)sidx * 32 + cg_ * 4);
    #pragma unroll
    for (int i = 0; i < 4; ++i) accA[i] += r.p[i] * w2;
  }
  for (int b2i = MAXD; b2i < c; b2i += 8){   // ultra-rare tail (deg > MAXD)
    int j = b2i + grp;
    bool valid = j < c;
    int sidx = valid ? (int)srcs[off + j] : 0;
    float wgt = valid ? __expf(fmaxf(Sv[sidx] + dvw, 0.f)) * inv : 0.f;
    F8 r; r.u = *(const uint4*)(G + (size_t)sidx * 32 + cg_ * 4);
    f16 wh = (f16)wgt; h2 w2 = {wh, wh};
    #pragma unroll
    for (int i = 0; i < 4; ++i) accA[i] += r.p[i] * w2;
  }
  #pragma unroll
  for (int i = 0; i < 4; ++i) accA[i] += accB[i];
  union FU { h2 v; float f; };
  #pragma unroll
  for (int i = 0; i < 4; ++i){
    FU a; a.v = accA[i];
    FU o1; o1.f = __shfl_xor(a.f,  8, 64); a.v = a.v + o1.v;
    FU o2; o2.f = __shfl_xor(a.f, 16, 64); a.v = a.v + o2.v;
    FU o3; o3.f = __shfl_xor(a.f, 32, 64); a.v = a.v + o3.v;
    accA[i] = a.v;
  }
  if (grp == 0){
    // lane cg_ holds out[cg_*8 .. +8): 4x h2 -> 8 fp32 + c64
    float4 o0, o1v;
    const float4* cv = (const float4*)(c64 + cg_ * 8);
    o0.x = (float)accA[0].x + cv[0].x;
    o0.y = (float)accA[0].y + cv[0].y;
    o0.z = (float)accA[1].x + cv[0].z;
    o0.w = (float)accA[1].y + cv[0].w;
    o1v.x = (float)accA[2].x + cv[1].x;
    o1v.y = (float)accA[2].y + cv[1].y;
    o1v.z = (float)accA[3].x + cv[1].z;
    o1v.w = (float)accA[3].y + cv[1].w;
    float4* op = (float4*)(out + (size_t)wid * DYY + cg_ * 8);
    op[0] = o0; op[1] = o1v;
  }
}

// kF: layer-2 aggregation in projected space. ONE node per wave
// (grid NN/4, 4 waves/block) — r9 form, kept (saved ~2.4 us vs 4/wave).
__global__ __launch_bounds__(256, 8) void kF(const u16* __restrict__ G2,
                                          const float* __restrict__ Sv2, const float* __restrict__ Dv2,
                                          const int* __restrict__ offs, const int* __restrict__ cnt,
                                          const u16* __restrict__ srcs,
                                          const float* __restrict__ c64,
                                          float* __restrict__ out){
  __shared__ int   s_i[4][MAXD];
  __shared__ float s_w[4][MAXD];
  int tid = threadIdx.x, wv = tid >> 6, lane = tid & 63;
  agg_node_out(G2, Sv2, Dv2, offs, cnt, srcs, c64, out,
               blockIdx.x * 4 + wv, lane, s_i[wv], s_w[wv]);
}

extern "C" void kernel_launch(void* const* d_in, const int* in_sizes, int n_in,
                              void* d_out, int out_size, void* d_ws, size_t ws_size,
                              hipStream_t stream) {
  const float* node_x = (const float*)d_in[0];
  const int* ei   = (const int*)d_in[1];
  const int* srcp = ei;
  const int* dstp = ei + EE;
  const float* W1  = (const float*)d_in[2];
  const float* as1 = (const float*)d_in[3];
  const float* ad1 = (const float*)d_in[4];
  const float* b1  = (const float*)d_in[5];
  const float* W2  = (const float*)d_in[6];
  const float* as2 = (const float*)d_in[7];
  const float* ad2 = (const float*)d_in[8];
  const float* b2  = (const float*)d_in[9];
  const float* Wo  = (const float*)d_in[10];
  const float* bo  = (const float*)d_in[11];

  // workspace carve: ~28 MB. buf (6.4 MB) aliases G2 (6.4 MB exactly):
  // buf dead after kD; kE writes G2.
  char* w = (char*)d_ws;
  u16*   Hbf1  = (u16*)w;  w += (size_t)NN * DD * 2;  // 12.8 MB layer-1 h (fp16)
  u32*   buf   = (u32*)w;
  u16*   G2    = (u16*)w;  w += (size_t)EE * 4;       // 6.4 MB (= NN*DYY*2)
  float* Sv1   = (float*)w; w += (size_t)NN * 4;
  float* Dv1   = (float*)w; w += (size_t)NN * 4;
  float* Sv2   = (float*)w; w += (size_t)NN * 4;
  float* Dv2   = (float*)w; w += (size_t)NN * 4;
  int*   cnt   = (int*)w;   w += (size_t)NN * 4;
  int*   offs  = (int*)w;   w += (size_t)NN * 4;
  int*   btot  = (int*)w;   w += 1024;
  int*   bbase = (int*)w;   w += 1024;
  int*   hist2d = (int*)w;  w += GB * 256 * 4;        // 200 KB
  u16*   srcs  = (u16*)w;   w += (size_t)EE * 2;      // 3.2 MB
  u16*   Wf1   = (u16*)w;   w += 32768;
  u16*   Wf2   = (u16*)w;   w += 32768;
  u16*   Wfo   = (u16*)w;   w += 16384;
  float* c64   = (float*)w; w += 256;

  const int TB = 256;

  kA_prep    <<<217,      TB, 0, stream>>>(dstp, hist2d, W1, W2, Wo, b2, bo,
                                           Wf1, Wf2, Wfo, c64);
  kBC        <<<GB + GMM, TB, 0, stream>>>(srcp, dstp, hist2d, btot, bbase, buf,
                                           node_x, Wf1, Hbf1, as1, ad1, Sv1, Dv1);
  kD_finalize<<<NB,       TB, 0, stream>>>(buf, btot, bbase, offs, cnt, srcs);
  kE         <<<NTILE,    TB, 0, stream>>>(Hbf1, Sv1, Dv1, offs, cnt, srcs, b1,
                                           Wf2, Wfo, as2, ad2, G2, Sv2, Dv2);
  kF         <<<NFB,      TB, 0, stream>>>(G2, Sv2, Dv2, offs, cnt, srcs, c64,
                                           (float*)d_out);
}